// Round 1
// baseline (2439.976 us; speedup 1.0000x reference)
//
#include <hip/hip_runtime.h>
#include <math.h>

#define F_IN 128
#define AH 16
#define ALPHA 0.2f

// ---------------- K1: new_h_mini = input @ w_mini + b_mini ----------------
// block = 256 threads = 16 nodes x 16 output channels. w_mini staged in LDS.
__global__ void k_mini(const float* __restrict__ input,
                       const float* __restrict__ w,
                       const float* __restrict__ b,
                       float* __restrict__ out, int n) {
    __shared__ float ws[F_IN * AH];
    for (int i = threadIdx.x; i < F_IN * AH; i += blockDim.x) ws[i] = w[i];
    __syncthreads();
    const int npb   = blockDim.x / AH;          // nodes per block (16)
    const int local = threadIdx.x / AH;
    const int j     = threadIdx.x % AH;
    for (int node = blockIdx.x * npb + local; node < n; node += gridDim.x * npb) {
        const float* row = input + (size_t)node * F_IN;
        float acc = b[j];
        #pragma unroll 8
        for (int f = 0; f < F_IN; ++f) acc += row[f] * ws[f * AH + j];
        out[(size_t)node * AH + j] = acc;
    }
}

// ---------------- K2: edge MLP -> fc0 (segment-summed) and raw fc1 --------
// fc1's linear layer differs from fc0 only by C[j] = sum_k ab[k]*(W1[k][j]+W1[16+k][j])
// (h_diff is shared), so one 48x16 pass serves both.
__global__ void k_edge_mlp(const int* __restrict__ src, const int* __restrict__ dst,
                           const float* __restrict__ h,         // N x 16
                           const float* __restrict__ lf1_w,     // 48 x 16
                           const float* __restrict__ lf1_b,     // 16
                           const float* __restrict__ lf2_w,     // 16
                           const float* __restrict__ lf2_b,     // 1
                           const float* __restrict__ ab,        // 16
                           float* __restrict__ fc0_sum,         // N (atomic)
                           float* __restrict__ cnt,             // N (atomic)
                           float* __restrict__ fc1_out,         // E
                           int e) {
    __shared__ float W1[48 * AH];
    __shared__ float B1[AH], W2[AH], C[AH];
    __shared__ float b2s;
    for (int i = threadIdx.x; i < 48 * AH; i += blockDim.x) W1[i] = lf1_w[i];
    if (threadIdx.x < AH) { B1[threadIdx.x] = lf1_b[threadIdx.x]; W2[threadIdx.x] = lf2_w[threadIdx.x]; }
    if (threadIdx.x == 0) b2s = lf2_b[0];
    __syncthreads();
    if (threadIdx.x < AH) {
        float c = 0.f;
        for (int k = 0; k < AH; ++k)
            c += ab[k] * (W1[k * AH + threadIdx.x] + W1[(AH + k) * AH + threadIdx.x]);
        C[threadIdx.x] = c;
    }
    __syncthreads();

    for (int idx = blockIdx.x * blockDim.x + threadIdx.x; idx < e;
         idx += gridDim.x * blockDim.x) {
        const int s = src[idx], d = dst[idx];
        float hs[AH], hd[AH], df[AH];
        const float4* ps = (const float4*)(h + (size_t)s * AH);
        const float4* pd = (const float4*)(h + (size_t)d * AH);
        #pragma unroll
        for (int q = 0; q < 4; ++q) {
            float4 v = ps[q];
            hs[4*q] = v.x; hs[4*q+1] = v.y; hs[4*q+2] = v.z; hs[4*q+3] = v.w;
        }
        #pragma unroll
        for (int q = 0; q < 4; ++q) {
            float4 v = pd[q];
            hd[4*q] = v.x; hd[4*q+1] = v.y; hd[4*q+2] = v.z; hd[4*q+3] = v.w;
        }
        #pragma unroll
        for (int k = 0; k < AH; ++k) df[k] = fabsf(hd[k] - hs[k]);

        float acc0 = b2s, acc1 = b2s;
        #pragma unroll
        for (int j = 0; j < AH; ++j) {
            float f = B1[j];
            #pragma unroll
            for (int k = 0; k < AH; ++k)
                f += hs[k] * W1[k * AH + j]
                   + hd[k] * W1[(AH + k) * AH + j]
                   + df[k] * W1[(2 * AH + k) * AH + j];
            const float f1 = f + C[j];
            acc0 += W2[j] * (f  > 0.f ? f  : ALPHA * f);
            acc1 += W2[j] * (f1 > 0.f ? f1 : ALPHA * f1);
        }
        const float fc0 = 1.f / (1.f + expf(-acc0));
        const float fc1 = 1.f / (1.f + expf(-acc1));
        atomicAdd(&fc0_sum[s], fc0);
        atomicAdd(&cnt[s], 1.0f);
        fc1_out[idx] = fc1;   // raw fc1, scaled into ef by K4
    }
}

// ---------------- K3: factor = fc0_sum / max(cnt, 1) ----------------------
__global__ void k_factor(const float* __restrict__ fc0_sum,
                         const float* __restrict__ cnt,
                         float* __restrict__ factor, int n) {
    int i = blockIdx.x * blockDim.x + threadIdx.x;
    if (i < n) factor[i] = fc0_sum[i] / fmaxf(cnt[i], 1.0f);
}

// ---------------- K4: ef = factor[s]*factor[d]*fc1, row-sum ---------------
__global__ void k_ef(const int* __restrict__ src, const int* __restrict__ dst,
                     const float* __restrict__ factor,
                     float* __restrict__ ef,            // in: raw fc1, out: ef
                     float* __restrict__ ef_row_sum,    // N (atomic)
                     int e) {
    for (int idx = blockIdx.x * blockDim.x + threadIdx.x; idx < e;
         idx += gridDim.x * blockDim.x) {
        const int s = src[idx], d = dst[idx];
        const float v = factor[s] * factor[d] * ef[idx];
        ef[idx] = v;
        atomicAdd(&ef_row_sum[s], v);
    }
}

// ---------------- K5: spmm[s] += ef * input[d] * deg[d] -------------------
// 64 lanes per edge, 2 features per lane; 4 edges per 256-thread block.
__global__ void k_spmm(const int* __restrict__ src, const int* __restrict__ dst,
                       const float* __restrict__ ef,
                       const float* __restrict__ input,
                       const float* __restrict__ degree,
                       float* __restrict__ spmm, int e) {
    const int lane = threadIdx.x & 63;
    const int eloc = threadIdx.x >> 6;
    const int idx  = blockIdx.x * 4 + eloc;
    if (idx >= e) return;
    const int s = src[idx], d = dst[idx];
    const float w = ef[idx] * degree[d];
    const float* in  = input + (size_t)d * F_IN;
    float*       out = spmm  + (size_t)s * F_IN;
    atomicAdd(&out[lane],      w * in[lane]);
    atomicAdd(&out[lane + 64], w * in[lane + 64]);
}

// ---------------- K6: final_h = spmm*deg + (1-aggr)*input (in place) ------
__global__ void k_final(const float* __restrict__ input,
                        const float* __restrict__ degree,
                        const float* __restrict__ ef_row_sum,
                        const float* __restrict__ adj_row,
                        float* __restrict__ out,   // holds spmm, overwritten
                        int n) {
    const size_t total  = (size_t)n * F_IN;
    const size_t stride = (size_t)gridDim.x * blockDim.x;
    for (size_t i = (size_t)blockIdx.x * blockDim.x + threadIdx.x; i < total; i += stride) {
        const int node = (int)(i >> 7);          // F_IN = 128
        const float aggr = ef_row_sum[node] / adj_row[node];
        out[i] = out[i] * degree[node] + (1.f - aggr) * input[i];
    }
}

extern "C" void kernel_launch(void* const* d_in, const int* in_sizes, int n_in,
                              void* d_out, int out_size, void* d_ws, size_t ws_size,
                              hipStream_t stream) {
    const float* input   = (const float*)d_in[0];
    const int*   edges   = (const int*)  d_in[1];
    const float* adj_row = (const float*)d_in[3];
    const float* degree  = (const float*)d_in[4];
    const float* w_mini  = (const float*)d_in[5];
    const float* b_mini  = (const float*)d_in[6];
    const float* ab      = (const float*)d_in[7];
    const float* lf1_w   = (const float*)d_in[8];
    const float* lf1_b   = (const float*)d_in[9];
    const float* lf2_w   = (const float*)d_in[10];
    const float* lf2_b   = (const float*)d_in[11];

    const int N = in_sizes[0] / F_IN;
    const int E = in_sizes[1] / 2;

    const int* src = edges;
    const int* dst = edges + E;

    float* final_h = (float*)d_out;              // N*128, used as spmm accumulator
    float* ef_out  = (float*)d_out + (size_t)N * F_IN;  // E

    // workspace layout (floats): h_mini[N*16] | fc0_sum[N] | cnt[N] | ef_row_sum[N] | factor[N]
    float* h_mini     = (float*)d_ws;
    float* fc0_sum    = h_mini + (size_t)N * AH;
    float* cnt        = fc0_sum + N;
    float* ef_row_sum = cnt + N;
    float* factor     = ef_row_sum + N;

    // zero the atomic accumulators (fc0_sum, cnt, ef_row_sum are contiguous)
    hipMemsetAsync(fc0_sum, 0, (size_t)3 * N * sizeof(float), stream);
    hipMemsetAsync(final_h, 0, (size_t)N * F_IN * sizeof(float), stream);

    // K1: node projection
    {
        int blocks = (N * AH + 255) / 256;
        k_mini<<<blocks, 256, 0, stream>>>(input, w_mini, b_mini, h_mini, N);
    }
    // K2: edge MLP (fc0 segment-sum + raw fc1)
    k_edge_mlp<<<2048, 256, 0, stream>>>(src, dst, h_mini, lf1_w, lf1_b, lf2_w, lf2_b,
                                         ab, fc0_sum, cnt, ef_out, E);
    // K3: per-node factor
    k_factor<<<(N + 255) / 256, 256, 0, stream>>>(fc0_sum, cnt, factor, N);
    // K4: ef scaling + row sum
    k_ef<<<2048, 256, 0, stream>>>(src, dst, factor, ef_out, ef_row_sum, E);
    // K5: SpMM scatter (accumulate into final_h region)
    k_spmm<<<(E + 3) / 4, 256, 0, stream>>>(src, dst, ef_out, input, degree, final_h, E);
    // K6: final combine
    k_final<<<4096, 256, 0, stream>>>(input, degree, ef_row_sum, adj_row, final_h, N);
}

// Round 2
// 1359.853 us; speedup vs baseline: 1.7943x; 1.7943x over previous
//
#include <hip/hip_runtime.h>
#include <math.h>

#define F_IN 128
#define AH 16
#define ALPHA 0.2f

// ============ K1: new_h_mini = input @ w_mini + b_mini ====================
// 16 nodes per 256-thread block; input rows staged coalesced into LDS.
__global__ void k_mini(const float* __restrict__ input,
                       const float* __restrict__ w,
                       const float* __restrict__ b,
                       float* __restrict__ out, int n) {
    __shared__ float ws[F_IN * AH];
    __shared__ float rows[16][F_IN + 1];   // +1 pad: bank-conflict-free column reads
    for (int i = threadIdx.x; i < F_IN * AH; i += blockDim.x) ws[i] = w[i];
    const int base = blockIdx.x * 16;
    for (int idx = threadIdx.x; idx < 16 * F_IN; idx += blockDim.x) {
        const int l = idx >> 7, f = idx & 127;
        const int node = base + l;
        rows[l][f] = (node < n) ? input[(size_t)node * F_IN + f] : 0.f;
    }
    __syncthreads();
    const int l = threadIdx.x >> 4;       // local node
    const int j = threadIdx.x & 15;       // out channel
    const int node = base + l;
    if (node < n) {
        float acc = b[j];
        #pragma unroll 8
        for (int f = 0; f < F_IN; ++f) acc += rows[l][f] * ws[f * AH + j];
        out[(size_t)node * AH + j] = acc;
    }
}

// ============ K2: histogram of src ========================================
__global__ void k_hist(const int* __restrict__ src, int* __restrict__ cnt, int e) {
    const int i = blockIdx.x * blockDim.x + threadIdx.x;
    if (i < e) atomicAdd(&cnt[src[i]], 1);
}

// ============ K3: exclusive scan of cnt -> row offsets ====================
#define SCAN_B 256
#define SCAN_I 4     // 1024 elements per block
__global__ void k_scan_part(const int* __restrict__ cnt, int* __restrict__ excl,
                            int* __restrict__ bsum, int n) {
    __shared__ int sh[SCAN_B];
    const int t = threadIdx.x;
    const int base = blockIdx.x * (SCAN_B * SCAN_I) + t * SCAN_I;
    int v[SCAN_I];
    int s = 0;
    #pragma unroll
    for (int k = 0; k < SCAN_I; ++k) { const int i = base + k; v[k] = (i < n) ? cnt[i] : 0; s += v[k]; }
    sh[t] = s; __syncthreads();
    for (int off = 1; off < SCAN_B; off <<= 1) {
        const int x = (t >= off) ? sh[t - off] : 0;
        __syncthreads();
        sh[t] += x;
        __syncthreads();
    }
    int r = sh[t] - s;                    // exclusive prefix of this thread
    if (t == SCAN_B - 1) bsum[blockIdx.x] = sh[t];
    #pragma unroll
    for (int k = 0; k < SCAN_I; ++k) { const int i = base + k; if (i < n) excl[i] = r; r += v[k]; }
}
__global__ void k_scan_tops(int* __restrict__ bsum, int nb) {
    __shared__ int sh[SCAN_B];
    const int t = threadIdx.x;
    const int v = (t < nb) ? bsum[t] : 0;
    sh[t] = v; __syncthreads();
    for (int off = 1; off < SCAN_B; off <<= 1) {
        const int x = (t >= off) ? sh[t - off] : 0;
        __syncthreads();
        sh[t] += x;
        __syncthreads();
    }
    if (t < nb) bsum[t] = sh[t] - v;
}
__global__ void k_scan_add(int* __restrict__ excl, const int* __restrict__ bsum, int n) {
    const int i = blockIdx.x * blockDim.x + threadIdx.x;
    if (i < n) excl[i] += bsum[i >> 10];
}

// ============ K4: scatter edges into CSR order ============================
// row_cur starts as exclusive offsets; afterwards row_cur[s] == end offset of s.
__global__ void k_scatter(const int* __restrict__ src, const int* __restrict__ dst,
                          int* __restrict__ row_cur,
                          int* __restrict__ sorted_eid, int* __restrict__ sorted_src,
                          int* __restrict__ sorted_dst, int e) {
    const int i = blockIdx.x * blockDim.x + threadIdx.x;
    if (i >= e) return;
    const int s = src[i];
    const int p = atomicAdd(&row_cur[s], 1);
    sorted_eid[p] = i;
    sorted_src[p] = s;
    sorted_dst[p] = dst[i];
}

// ============ K5: edge MLP in sorted order -> fc0_s, fc1_s ================
// fc1's first layer differs from fc0's only by C[j] (h_diff shared), so one
// 768-FMA pass serves both. Register-lean: only f[16] + one float4 pair live.
__global__ void k_mlp(const int* __restrict__ sorted_src, const int* __restrict__ sorted_dst,
                      const float* __restrict__ h,
                      const float* __restrict__ lf1_w, const float* __restrict__ lf1_b,
                      const float* __restrict__ lf2_w, const float* __restrict__ lf2_b,
                      const float* __restrict__ ab,
                      float* __restrict__ fc0_s, float* __restrict__ fc1_s, int e) {
    __shared__ float4 W1[48 * 4];         // [row][quad of 4 cols]
    __shared__ float B1[AH], W2[AH], Cj[AH];
    __shared__ float b2s;
    for (int i = threadIdx.x; i < 48 * 4; i += blockDim.x)
        W1[i] = ((const float4*)lf1_w)[i];
    if (threadIdx.x < AH) { B1[threadIdx.x] = lf1_b[threadIdx.x]; W2[threadIdx.x] = lf2_w[threadIdx.x]; }
    if (threadIdx.x == 0) b2s = lf2_b[0];
    if (threadIdx.x < AH) {
        float c = 0.f;
        for (int k = 0; k < AH; ++k)
            c += ab[k] * (lf1_w[k * AH + threadIdx.x] + lf1_w[(AH + k) * AH + threadIdx.x]);
        Cj[threadIdx.x] = c;
    }
    __syncthreads();

    const int i = blockIdx.x * blockDim.x + threadIdx.x;
    if (i >= e) return;
    const int s = sorted_src[i], d = sorted_dst[i];
    const float4* ps = (const float4*)(h + (size_t)s * AH);
    const float4* pd = (const float4*)(h + (size_t)d * AH);

    float f[AH];
    #pragma unroll
    for (int j = 0; j < AH; ++j) f[j] = B1[j];

    #pragma unroll
    for (int q = 0; q < 4; ++q) {
        const float4 a = ps[q];
        const float4 b4 = pd[q];
        const float hsv[4] = { a.x, a.y, a.z, a.w };
        const float hdv[4] = { b4.x, b4.y, b4.z, b4.w };
        #pragma unroll
        for (int kk = 0; kk < 4; ++kk) {
            const int k = 4 * q + kk;
            const float hs = hsv[kk];
            const float hd = hdv[kk];
            const float df = fabsf(hd - hs);
            #pragma unroll
            for (int m = 0; m < 4; ++m) {
                const float4 w0 = W1[k * 4 + m];
                const float4 w1 = W1[(AH + k) * 4 + m];
                const float4 w2 = W1[(2 * AH + k) * 4 + m];
                f[4 * m + 0] += hs * w0.x + hd * w1.x + df * w2.x;
                f[4 * m + 1] += hs * w0.y + hd * w1.y + df * w2.y;
                f[4 * m + 2] += hs * w0.z + hd * w1.z + df * w2.z;
                f[4 * m + 3] += hs * w0.w + hd * w1.w + df * w2.w;
            }
        }
    }
    float acc0 = b2s, acc1 = b2s;
    #pragma unroll
    for (int j = 0; j < AH; ++j) {
        const float v0 = f[j];
        const float v1 = f[j] + Cj[j];
        acc0 += W2[j] * (v0 > 0.f ? v0 : ALPHA * v0);
        acc1 += W2[j] * (v1 > 0.f ? v1 : ALPHA * v1);
    }
    fc0_s[i] = 1.f / (1.f + expf(-acc0));
    fc1_s[i] = 1.f / (1.f + expf(-acc1));
}

// ============ K6: per-node factor = sum(fc0)/max(cnt,1) ===================
__global__ void k_factor(const int* __restrict__ row_end, const int* __restrict__ cnt,
                         const float* __restrict__ fc0_s, float* __restrict__ factor, int n) {
    const int i = blockIdx.x * blockDim.x + threadIdx.x;
    if (i >= n) return;
    const int end = row_end[i];
    const int c = cnt[i];
    float s = 0.f;
    for (int p = end - c; p < end; ++p) s += fc0_s[p];
    factor[i] = s / fmaxf((float)c, 1.f);
}

// ============ K7: fused ef + row-sum + SpMM + final combine ===============
// One 64-lane wave per node; 2 features per lane. No atomics anywhere.
__global__ void k_spmm_final(const int* __restrict__ row_end, const int* __restrict__ cnt,
                             const int* __restrict__ sorted_dst, const int* __restrict__ sorted_eid,
                             const float* __restrict__ fc1_s, const float* __restrict__ factor,
                             const float* __restrict__ input, const float* __restrict__ degree,
                             const float* __restrict__ adj_row,
                             float* __restrict__ out_h, float* __restrict__ ef_out, int n) {
    const int wid  = (blockIdx.x * blockDim.x + threadIdx.x) >> 6;
    const int lane = threadIdx.x & 63;
    if (wid >= n) return;
    const int end = row_end[wid];
    const int c   = cnt[wid];
    const float fnode = factor[wid];
    float acc0 = 0.f, acc1 = 0.f, efsum = 0.f;
    for (int p = end - c; p < end; ++p) {
        const int d = sorted_dst[p];                 // wave-uniform (broadcast)
        const float ef = fnode * factor[d] * fc1_s[p];
        if (lane == (p & 63)) ef_out[sorted_eid[p]] = ef;
        efsum += ef;
        const float w = ef * degree[d];
        const float* in = input + (size_t)d * F_IN;
        acc0 += w * in[lane];
        acc1 += w * in[lane + 64];
    }
    const float aggr = efsum / adj_row[wid];
    const float dg = degree[wid];
    const float* inn = input + (size_t)wid * F_IN;
    out_h[(size_t)wid * F_IN + lane]      = acc0 * dg + (1.f - aggr) * inn[lane];
    out_h[(size_t)wid * F_IN + lane + 64] = acc1 * dg + (1.f - aggr) * inn[lane + 64];
}

extern "C" void kernel_launch(void* const* d_in, const int* in_sizes, int n_in,
                              void* d_out, int out_size, void* d_ws, size_t ws_size,
                              hipStream_t stream) {
    const float* input   = (const float*)d_in[0];
    const int*   edges   = (const int*)  d_in[1];
    const float* adj_row = (const float*)d_in[3];
    const float* degree  = (const float*)d_in[4];
    const float* w_mini  = (const float*)d_in[5];
    const float* b_mini  = (const float*)d_in[6];
    const float* ab      = (const float*)d_in[7];
    const float* lf1_w   = (const float*)d_in[8];
    const float* lf1_b   = (const float*)d_in[9];
    const float* lf2_w   = (const float*)d_in[10];
    const float* lf2_b   = (const float*)d_in[11];

    const int N = in_sizes[0] / F_IN;
    const int E = in_sizes[1] / 2;
    const int* src = edges;
    const int* dst = edges + E;

    float* final_h = (float*)d_out;
    float* ef_out  = (float*)d_out + (size_t)N * F_IN;

    // workspace layout (all 4-byte elems, 16B-aligned sections)
    float* h_mini     = (float*)d_ws;                 // N*16
    float* fc0_s      = h_mini + (size_t)N * AH;      // E
    float* fc1_s      = fc0_s + E;                    // E
    float* factor     = fc1_s + E;                    // N
    int*   cnt        = (int*)(factor + N);           // N
    int*   row_cur    = cnt + N;                      // N (excl offsets -> end offsets)
    int*   bsum       = row_cur + N;                  // 1024
    int*   sorted_eid = bsum + 1024;                  // E
    int*   sorted_src = sorted_eid + E;               // E
    int*   sorted_dst = sorted_src + E;               // E

    hipMemsetAsync(cnt, 0, (size_t)N * sizeof(int), stream);

    // K1: node projection
    k_mini<<<(N + 15) / 16, 256, 0, stream>>>(input, w_mini, b_mini, h_mini, N);
    // K2: degree histogram
    k_hist<<<(E + 255) / 256, 256, 0, stream>>>(src, cnt, E);
    // K3: exclusive scan -> row_cur
    {
        const int nb = (N + SCAN_B * SCAN_I - 1) / (SCAN_B * SCAN_I);   // 98 for N=100000
        k_scan_part<<<nb, SCAN_B, 0, stream>>>(cnt, row_cur, bsum, N);
        k_scan_tops<<<1, SCAN_B, 0, stream>>>(bsum, nb);
        k_scan_add<<<(N + 255) / 256, 256, 0, stream>>>(row_cur, bsum, N);
    }
    // K4: CSR scatter (row_cur becomes end offsets)
    k_scatter<<<(E + 255) / 256, 256, 0, stream>>>(src, dst, row_cur,
                                                   sorted_eid, sorted_src, sorted_dst, E);
    // K5: edge MLP (sorted order, no atomics)
    k_mlp<<<(E + 255) / 256, 256, 0, stream>>>(sorted_src, sorted_dst, h_mini,
                                               lf1_w, lf1_b, lf2_w, lf2_b, ab,
                                               fc0_s, fc1_s, E);
    // K6: per-node factor
    k_factor<<<(N + 255) / 256, 256, 0, stream>>>(row_cur, cnt, fc0_s, factor, N);
    // K7: fused ef + SpMM + final (wave per node)
    k_spmm_final<<<(N * 64 + 255) / 256, 256, 0, stream>>>(row_cur, cnt, sorted_dst, sorted_eid,
                                                           fc1_s, factor, input, degree, adj_row,
                                                           final_h, ef_out, N);
}

// Round 3
// 603.564 us; speedup vs baseline: 4.0426x; 2.2530x over previous
//
#include <hip/hip_runtime.h>
#include <math.h>

#define F_IN 128
#define AH 16
#define ALPHA 0.2f

// ============ K1: new_h_mini = input @ w_mini + b_mini ====================
__global__ void k_mini(const float* __restrict__ input,
                       const float* __restrict__ w,
                       const float* __restrict__ b,
                       float* __restrict__ out, int n) {
    __shared__ float ws[F_IN * AH];
    __shared__ float rows[16][F_IN + 1];
    for (int i = threadIdx.x; i < F_IN * AH; i += blockDim.x) ws[i] = w[i];
    const int base = blockIdx.x * 16;
    for (int idx = threadIdx.x; idx < 16 * F_IN; idx += blockDim.x) {
        const int l = idx >> 7, f = idx & 127;
        const int node = base + l;
        rows[l][f] = (node < n) ? input[(size_t)node * F_IN + f] : 0.f;
    }
    __syncthreads();
    const int l = threadIdx.x >> 4;
    const int j = threadIdx.x & 15;
    const int node = base + l;
    if (node < n) {
        float acc = b[j];
        #pragma unroll 8
        for (int f = 0; f < F_IN; ++f) acc += rows[l][f] * ws[f * AH + j];
        out[(size_t)node * AH + j] = acc;
    }
}

// ============ K-prep: Cj[j] = sum_k ab[k]*(W1[k][j] + W1[16+k][j]) ========
__global__ void k_prep(const float* __restrict__ lf1_w, const float* __restrict__ ab,
                       float* __restrict__ Cj) {
    const int j = threadIdx.x;
    if (j < AH) {
        float c = 0.f;
        for (int k = 0; k < AH; ++k)
            c += ab[k] * (lf1_w[k * AH + j] + lf1_w[(AH + k) * AH + j]);
        Cj[j] = c;
    }
}

// ============ K2: histogram of src ========================================
__global__ void k_hist(const int* __restrict__ src, int* __restrict__ cnt, int e) {
    const int i = blockIdx.x * blockDim.x + threadIdx.x;
    if (i < e) atomicAdd(&cnt[src[i]], 1);
}

// ============ K3: exclusive scan ==========================================
#define SCAN_B 256
#define SCAN_I 4
__global__ void k_scan_part(const int* __restrict__ cnt, int* __restrict__ excl,
                            int* __restrict__ bsum, int n) {
    __shared__ int sh[SCAN_B];
    const int t = threadIdx.x;
    const int base = blockIdx.x * (SCAN_B * SCAN_I) + t * SCAN_I;
    int v[SCAN_I];
    int s = 0;
    #pragma unroll
    for (int k = 0; k < SCAN_I; ++k) { const int i = base + k; v[k] = (i < n) ? cnt[i] : 0; s += v[k]; }
    sh[t] = s; __syncthreads();
    for (int off = 1; off < SCAN_B; off <<= 1) {
        const int x = (t >= off) ? sh[t - off] : 0;
        __syncthreads();
        sh[t] += x;
        __syncthreads();
    }
    int r = sh[t] - s;
    if (t == SCAN_B - 1) bsum[blockIdx.x] = sh[t];
    #pragma unroll
    for (int k = 0; k < SCAN_I; ++k) { const int i = base + k; if (i < n) excl[i] = r; r += v[k]; }
}
__global__ void k_scan_tops(int* __restrict__ bsum, int nb) {
    __shared__ int sh[SCAN_B];
    const int t = threadIdx.x;
    const int v = (t < nb) ? bsum[t] : 0;
    sh[t] = v; __syncthreads();
    for (int off = 1; off < SCAN_B; off <<= 1) {
        const int x = (t >= off) ? sh[t - off] : 0;
        __syncthreads();
        sh[t] += x;
        __syncthreads();
    }
    if (t < nb) bsum[t] = sh[t] - v;
}
__global__ void k_scan_add(int* __restrict__ excl, const int* __restrict__ bsum, int n) {
    const int i = blockIdx.x * blockDim.x + threadIdx.x;
    if (i < n) excl[i] += bsum[i >> 10];
}

// ============ K4: scatter edges into CSR order ============================
__global__ void k_scatter(const int* __restrict__ src, const int* __restrict__ dst,
                          int* __restrict__ row_cur,
                          int* __restrict__ sorted_src, int2* __restrict__ sorted_de, int e) {
    const int i = blockIdx.x * blockDim.x + threadIdx.x;
    if (i >= e) return;
    const int s = src[i];
    const int p = atomicAdd(&row_cur[s], 1);
    sorted_src[p] = s;
    sorted_de[p] = make_int2(dst[i], i);
}

// ============ K5: edge MLP, sorted order ==================================
// Named scalar accumulators (cannot spill to scratch); all weights read via
// wave-uniform literal-offset loads (scalar cache), zero LDS.
#define ROW4(base, val) \
    w = Wv[(base) * 4 + 0]; f0  += (val) * w.x; f1  += (val) * w.y; f2  += (val) * w.z; f3  += (val) * w.w; \
    w = Wv[(base) * 4 + 1]; f4  += (val) * w.x; f5  += (val) * w.y; f6  += (val) * w.z; f7  += (val) * w.w; \
    w = Wv[(base) * 4 + 2]; f8  += (val) * w.x; f9  += (val) * w.y; f10 += (val) * w.z; f11 += (val) * w.w; \
    w = Wv[(base) * 4 + 3]; f12 += (val) * w.x; f13 += (val) * w.y; f14 += (val) * w.z; f15 += (val) * w.w;

#define KSTEP(k, hs, hd) { \
    const float df_ = fabsf((hd) - (hs)); float4 w; \
    ROW4((k), (hs)) ROW4((16 + (k)), (hd)) ROW4((32 + (k)), df_) }

#define TAIL(j, fj) { \
    const float w2_ = lf2_w[j]; const float c_ = Cj[j]; \
    acc0 += w2_ * ((fj) > 0.f ? (fj) : ALPHA * (fj)); \
    const float v1_ = (fj) + c_; \
    acc1 += w2_ * (v1_ > 0.f ? v1_ : ALPHA * v1_); }

__global__ __launch_bounds__(256, 4)
void k_mlp(const int* __restrict__ sorted_src, const int2* __restrict__ sorted_de,
           const float* __restrict__ h,
           const float* __restrict__ lf1_w, const float* __restrict__ lf1_b,
           const float* __restrict__ lf2_w, const float* __restrict__ lf2_b,
           const float* __restrict__ Cj,
           float* __restrict__ fc0_s, float* __restrict__ fc1_s, int e) {
    const int i = blockIdx.x * blockDim.x + threadIdx.x;
    if (i >= e) return;
    const int s = sorted_src[i];
    const int d = sorted_de[i].x;
    const float4* __restrict__ ps = (const float4*)(h + (size_t)s * AH);
    const float4* __restrict__ pd = (const float4*)(h + (size_t)d * AH);
    const float4* __restrict__ Wv = (const float4*)lf1_w;

    float f0  = lf1_b[0],  f1  = lf1_b[1],  f2  = lf1_b[2],  f3  = lf1_b[3];
    float f4  = lf1_b[4],  f5  = lf1_b[5],  f6  = lf1_b[6],  f7  = lf1_b[7];
    float f8  = lf1_b[8],  f9  = lf1_b[9],  f10 = lf1_b[10], f11 = lf1_b[11];
    float f12 = lf1_b[12], f13 = lf1_b[13], f14 = lf1_b[14], f15 = lf1_b[15];

    float4 a, b4;
    a = ps[0]; b4 = pd[0];
    KSTEP(0,  a.x, b4.x) KSTEP(1,  a.y, b4.y) KSTEP(2,  a.z, b4.z) KSTEP(3,  a.w, b4.w)
    a = ps[1]; b4 = pd[1];
    KSTEP(4,  a.x, b4.x) KSTEP(5,  a.y, b4.y) KSTEP(6,  a.z, b4.z) KSTEP(7,  a.w, b4.w)
    a = ps[2]; b4 = pd[2];
    KSTEP(8,  a.x, b4.x) KSTEP(9,  a.y, b4.y) KSTEP(10, a.z, b4.z) KSTEP(11, a.w, b4.w)
    a = ps[3]; b4 = pd[3];
    KSTEP(12, a.x, b4.x) KSTEP(13, a.y, b4.y) KSTEP(14, a.z, b4.z) KSTEP(15, a.w, b4.w)

    float acc0 = lf2_b[0], acc1 = lf2_b[0];
    TAIL(0, f0)  TAIL(1, f1)  TAIL(2, f2)   TAIL(3, f3)
    TAIL(4, f4)  TAIL(5, f5)  TAIL(6, f6)   TAIL(7, f7)
    TAIL(8, f8)  TAIL(9, f9)  TAIL(10, f10) TAIL(11, f11)
    TAIL(12, f12) TAIL(13, f13) TAIL(14, f14) TAIL(15, f15)

    fc0_s[i] = 1.f / (1.f + expf(-acc0));
    fc1_s[i] = 1.f / (1.f + expf(-acc1));
}

// ============ K6: per-node factor =========================================
__global__ void k_factor(const int* __restrict__ row_end, const int* __restrict__ cnt,
                         const float* __restrict__ fc0_s, float* __restrict__ factor, int n) {
    const int i = blockIdx.x * blockDim.x + threadIdx.x;
    if (i >= n) return;
    const int end = row_end[i];
    const int c = cnt[i];
    float s = 0.f;
    for (int p = end - c; p < end; ++p) s += fc0_s[p];
    factor[i] = s / fmaxf((float)c, 1.f);
}

// ============ K7: fused ef + row-sum + SpMM + final combine ===============
__global__ void k_spmm_final(const int* __restrict__ row_end, const int* __restrict__ cnt,
                             const int2* __restrict__ sorted_de,
                             const float* __restrict__ fc1_s, const float* __restrict__ factor,
                             const float* __restrict__ input, const float* __restrict__ degree,
                             const float* __restrict__ adj_row,
                             float* __restrict__ out_h, float* __restrict__ ef_out, int n) {
    const int wid  = (blockIdx.x * blockDim.x + threadIdx.x) >> 6;
    const int lane = threadIdx.x & 63;
    if (wid >= n) return;
    const int end = row_end[wid];
    const int c   = cnt[wid];
    const float fnode = factor[wid];
    float acc0 = 0.f, acc1 = 0.f, efsum = 0.f;
    for (int p = end - c; p < end; ++p) {
        const int2 de = sorted_de[p];              // wave-uniform
        const float ef = fnode * factor[de.x] * fc1_s[p];
        if (lane == (p & 63)) ef_out[de.y] = ef;
        efsum += ef;
        const float w = ef * degree[de.x];
        const float* in = input + (size_t)de.x * F_IN;
        acc0 += w * in[lane];
        acc1 += w * in[lane + 64];
    }
    const float aggr = efsum / adj_row[wid];
    const float dg = degree[wid];
    const float* inn = input + (size_t)wid * F_IN;
    out_h[(size_t)wid * F_IN + lane]      = acc0 * dg + (1.f - aggr) * inn[lane];
    out_h[(size_t)wid * F_IN + lane + 64] = acc1 * dg + (1.f - aggr) * inn[lane + 64];
}

extern "C" void kernel_launch(void* const* d_in, const int* in_sizes, int n_in,
                              void* d_out, int out_size, void* d_ws, size_t ws_size,
                              hipStream_t stream) {
    const float* input   = (const float*)d_in[0];
    const int*   edges   = (const int*)  d_in[1];
    const float* adj_row = (const float*)d_in[3];
    const float* degree  = (const float*)d_in[4];
    const float* w_mini  = (const float*)d_in[5];
    const float* b_mini  = (const float*)d_in[6];
    const float* ab      = (const float*)d_in[7];
    const float* lf1_w   = (const float*)d_in[8];
    const float* lf1_b   = (const float*)d_in[9];
    const float* lf2_w   = (const float*)d_in[10];
    const float* lf2_b   = (const float*)d_in[11];

    const int N = in_sizes[0] / F_IN;
    const int E = in_sizes[1] / 2;
    const int* src = edges;
    const int* dst = edges + E;

    float* final_h = (float*)d_out;
    float* ef_out  = (float*)d_out + (size_t)N * F_IN;

    // workspace layout (4-byte elems; all section sizes even -> int2 aligned)
    float* h_mini     = (float*)d_ws;                 // N*16
    float* fc0_s      = h_mini + (size_t)N * AH;      // E
    float* fc1_s      = fc0_s + E;                    // E
    float* factor     = fc1_s + E;                    // N
    float* Cj         = factor + N;                   // 16
    int*   cnt        = (int*)(Cj + 16);              // N
    int*   row_cur    = cnt + N;                      // N
    int*   bsum       = row_cur + N;                  // 1024
    int*   sorted_src = bsum + 1024;                  // E
    int2*  sorted_de  = (int2*)(sorted_src + E);      // E (dst, eid)

    hipMemsetAsync(cnt, 0, (size_t)N * sizeof(int), stream);

    k_mini<<<(N + 15) / 16, 256, 0, stream>>>(input, w_mini, b_mini, h_mini, N);
    k_prep<<<1, 64, 0, stream>>>(lf1_w, ab, Cj);
    k_hist<<<(E + 255) / 256, 256, 0, stream>>>(src, cnt, E);
    {
        const int nb = (N + SCAN_B * SCAN_I - 1) / (SCAN_B * SCAN_I);
        k_scan_part<<<nb, SCAN_B, 0, stream>>>(cnt, row_cur, bsum, N);
        k_scan_tops<<<1, SCAN_B, 0, stream>>>(bsum, nb);
        k_scan_add<<<(N + 255) / 256, 256, 0, stream>>>(row_cur, bsum, N);
    }
    k_scatter<<<(E + 255) / 256, 256, 0, stream>>>(src, dst, row_cur, sorted_src, sorted_de, E);
    k_mlp<<<(E + 255) / 256, 256, 0, stream>>>(sorted_src, sorted_de, h_mini,
                                               lf1_w, lf1_b, lf2_w, lf2_b, Cj,
                                               fc0_s, fc1_s, E);
    k_factor<<<(N + 255) / 256, 256, 0, stream>>>(row_cur, cnt, fc0_s, factor, N);
    k_spmm_final<<<(N * 64 + 255) / 256, 256, 0, stream>>>(row_cur, cnt, sorted_de,
                                                           fc1_s, factor, input, degree, adj_row,
                                                           final_h, ef_out, N);
}

// Round 4
// 469.314 us; speedup vs baseline: 5.1990x; 1.2861x over previous
//
#include <hip/hip_runtime.h>
#include <math.h>

#define F_IN 128
#define AH 16
#define ALPHA 0.2f

// ============ K1: new_h_mini = input @ w_mini + b_mini ====================
__global__ void k_mini(const float* __restrict__ input,
                       const float* __restrict__ w,
                       const float* __restrict__ b,
                       float* __restrict__ out, int n) {
    __shared__ float ws[F_IN * AH];
    __shared__ float rows[16][F_IN + 1];
    for (int i = threadIdx.x; i < F_IN * AH; i += blockDim.x) ws[i] = w[i];
    const int base = blockIdx.x * 16;
    for (int idx = threadIdx.x; idx < 16 * F_IN; idx += blockDim.x) {
        const int l = idx >> 7, f = idx & 127;
        const int node = base + l;
        rows[l][f] = (node < n) ? input[(size_t)node * F_IN + f] : 0.f;
    }
    __syncthreads();
    const int l = threadIdx.x >> 4;
    const int j = threadIdx.x & 15;
    const int node = base + l;
    if (node < n) {
        float acc = b[j];
        #pragma unroll 8
        for (int f = 0; f < F_IN; ++f) acc += rows[l][f] * ws[f * AH + j];
        out[(size_t)node * AH + j] = acc;
    }
}

// ============ K-prep: Cj[j] = sum_k ab[k]*(W1[k][j] + W1[16+k][j]) ========
__global__ void k_prep(const float* __restrict__ lf1_w, const float* __restrict__ ab,
                       float* __restrict__ Cj) {
    const int j = threadIdx.x;
    if (j < AH) {
        float c = 0.f;
        for (int k = 0; k < AH; ++k)
            c += ab[k] * (lf1_w[k * AH + j] + lf1_w[(AH + k) * AH + j]);
        Cj[j] = c;
    }
}

// ============ K-scale: sim[node][j] = pack2xbf16(input[node][2j..2j+1]*deg) =
__device__ __forceinline__ unsigned f2bf_rn(float x) {
    unsigned u = __float_as_uint(x);
    return (u + 0x7fffu + ((u >> 16) & 1u)) >> 16;
}
__global__ void k_scale(const float* __restrict__ input, const float* __restrict__ degree,
                        unsigned* __restrict__ sim, int n) {
    const int i = blockIdx.x * blockDim.x + threadIdx.x;   // one per feature pair
    if (i >= n * 64) return;
    const int node = i >> 6;
    const float dg = degree[node];
    const float2 v = *(const float2*)(input + (size_t)i * 2);
    sim[i] = (f2bf_rn(v.y * dg) << 16) | f2bf_rn(v.x * dg);
}

// ============ K2: histogram of src ========================================
__global__ void k_hist(const int* __restrict__ src, int* __restrict__ cnt, int e) {
    const int i = blockIdx.x * blockDim.x + threadIdx.x;
    if (i < e) atomicAdd(&cnt[src[i]], 1);
}

// ============ K3: exclusive scan ==========================================
#define SCAN_B 256
#define SCAN_I 4
__global__ void k_scan_part(const int* __restrict__ cnt, int* __restrict__ excl,
                            int* __restrict__ bsum, int n) {
    __shared__ int sh[SCAN_B];
    const int t = threadIdx.x;
    const int base = blockIdx.x * (SCAN_B * SCAN_I) + t * SCAN_I;
    int v[SCAN_I];
    int s = 0;
    #pragma unroll
    for (int k = 0; k < SCAN_I; ++k) { const int i = base + k; v[k] = (i < n) ? cnt[i] : 0; s += v[k]; }
    sh[t] = s; __syncthreads();
    for (int off = 1; off < SCAN_B; off <<= 1) {
        const int x = (t >= off) ? sh[t - off] : 0;
        __syncthreads();
        sh[t] += x;
        __syncthreads();
    }
    int r = sh[t] - s;
    if (t == SCAN_B - 1) bsum[blockIdx.x] = sh[t];
    #pragma unroll
    for (int k = 0; k < SCAN_I; ++k) { const int i = base + k; if (i < n) excl[i] = r; r += v[k]; }
}
__global__ void k_scan_tops(int* __restrict__ bsum, int nb) {
    __shared__ int sh[SCAN_B];
    const int t = threadIdx.x;
    const int v = (t < nb) ? bsum[t] : 0;
    sh[t] = v; __syncthreads();
    for (int off = 1; off < SCAN_B; off <<= 1) {
        const int x = (t >= off) ? sh[t - off] : 0;
        __syncthreads();
        sh[t] += x;
        __syncthreads();
    }
    if (t < nb) bsum[t] = sh[t] - v;
}
__global__ void k_scan_add(int* __restrict__ excl, const int* __restrict__ bsum, int n) {
    const int i = blockIdx.x * blockDim.x + threadIdx.x;
    if (i < n) excl[i] += bsum[i >> 10];
}

// ============ K4: scatter edges into CSR order ============================
__global__ void k_scatter(const int* __restrict__ src, const int* __restrict__ dst,
                          int* __restrict__ row_cur,
                          int* __restrict__ sorted_src, int2* __restrict__ sorted_de, int e) {
    const int i = blockIdx.x * blockDim.x + threadIdx.x;
    if (i >= e) return;
    const int s = src[i];
    const int p = atomicAdd(&row_cur[s], 1);
    sorted_src[p] = s;
    sorted_de[p] = make_int2(dst[i], i);
}

// ============ K5: edge MLP, sorted order ==================================
#define ROW4(base, val) \
    w = Wv[(base) * 4 + 0]; f0  += (val) * w.x; f1  += (val) * w.y; f2  += (val) * w.z; f3  += (val) * w.w; \
    w = Wv[(base) * 4 + 1]; f4  += (val) * w.x; f5  += (val) * w.y; f6  += (val) * w.z; f7  += (val) * w.w; \
    w = Wv[(base) * 4 + 2]; f8  += (val) * w.x; f9  += (val) * w.y; f10 += (val) * w.z; f11 += (val) * w.w; \
    w = Wv[(base) * 4 + 3]; f12 += (val) * w.x; f13 += (val) * w.y; f14 += (val) * w.z; f15 += (val) * w.w;

#define KSTEP(k, hs, hd) { \
    const float df_ = fabsf((hd) - (hs)); float4 w; \
    ROW4((k), (hs)) ROW4((16 + (k)), (hd)) ROW4((32 + (k)), df_) }

#define TAIL(j, fj) { \
    const float w2_ = lf2_w[j]; const float c_ = Cj[j]; \
    acc0 += w2_ * ((fj) > 0.f ? (fj) : ALPHA * (fj)); \
    const float v1_ = (fj) + c_; \
    acc1 += w2_ * (v1_ > 0.f ? v1_ : ALPHA * v1_); }

__global__ __launch_bounds__(256, 4)
void k_mlp(const int* __restrict__ sorted_src, const int2* __restrict__ sorted_de,
           const float* __restrict__ h,
           const float* __restrict__ lf1_w, const float* __restrict__ lf1_b,
           const float* __restrict__ lf2_w, const float* __restrict__ lf2_b,
           const float* __restrict__ Cj,
           float* __restrict__ fc0_s, float* __restrict__ fc1_s, int e) {
    const int i = blockIdx.x * blockDim.x + threadIdx.x;
    if (i >= e) return;
    const int s = sorted_src[i];
    const int d = sorted_de[i].x;
    const float4* __restrict__ ps = (const float4*)(h + (size_t)s * AH);
    const float4* __restrict__ pd = (const float4*)(h + (size_t)d * AH);
    const float4* __restrict__ Wv = (const float4*)lf1_w;

    float f0  = lf1_b[0],  f1  = lf1_b[1],  f2  = lf1_b[2],  f3  = lf1_b[3];
    float f4  = lf1_b[4],  f5  = lf1_b[5],  f6  = lf1_b[6],  f7  = lf1_b[7];
    float f8  = lf1_b[8],  f9  = lf1_b[9],  f10 = lf1_b[10], f11 = lf1_b[11];
    float f12 = lf1_b[12], f13 = lf1_b[13], f14 = lf1_b[14], f15 = lf1_b[15];

    float4 a, b4;
    a = ps[0]; b4 = pd[0];
    KSTEP(0,  a.x, b4.x) KSTEP(1,  a.y, b4.y) KSTEP(2,  a.z, b4.z) KSTEP(3,  a.w, b4.w)
    a = ps[1]; b4 = pd[1];
    KSTEP(4,  a.x, b4.x) KSTEP(5,  a.y, b4.y) KSTEP(6,  a.z, b4.z) KSTEP(7,  a.w, b4.w)
    a = ps[2]; b4 = pd[2];
    KSTEP(8,  a.x, b4.x) KSTEP(9,  a.y, b4.y) KSTEP(10, a.z, b4.z) KSTEP(11, a.w, b4.w)
    a = ps[3]; b4 = pd[3];
    KSTEP(12, a.x, b4.x) KSTEP(13, a.y, b4.y) KSTEP(14, a.z, b4.z) KSTEP(15, a.w, b4.w)

    float acc0 = lf2_b[0], acc1 = lf2_b[0];
    TAIL(0, f0)  TAIL(1, f1)  TAIL(2, f2)   TAIL(3, f3)
    TAIL(4, f4)  TAIL(5, f5)  TAIL(6, f6)   TAIL(7, f7)
    TAIL(8, f8)  TAIL(9, f9)  TAIL(10, f10) TAIL(11, f11)
    TAIL(12, f12) TAIL(13, f13) TAIL(14, f14) TAIL(15, f15)

    fc0_s[i] = 1.f / (1.f + expf(-acc0));
    fc1_s[i] = 1.f / (1.f + expf(-acc1));
}

// ============ K6: per-node factor =========================================
__global__ void k_factor(const int* __restrict__ row_end, const int* __restrict__ cnt,
                         const float* __restrict__ fc0_s, float* __restrict__ factor, int n) {
    const int i = blockIdx.x * blockDim.x + threadIdx.x;
    if (i >= n) return;
    const int end = row_end[i];
    const int c = cnt[i];
    float s = 0.f;
    for (int p = end - c; p < end; ++p) s += fc0_s[p];
    factor[i] = s / fmaxf((float)c, 1.f);
}

// ============ K7: fused ef + row-sum + SpMM + final combine ===============
// One wave per node; lane owns features (2*lane, 2*lane+1). Edge loop
// unrolled x4 so 4 row-gathers are in flight per wave. USEBF=1 gathers
// pre-scaled bf16 pairs (4B/lane/edge), USEBF=0 gathers f32 pairs (8B).
template <int USEBF>
__global__ void k_spmm_final(const int* __restrict__ row_end, const int* __restrict__ cnt,
                             const int2* __restrict__ sorted_de,
                             const float* __restrict__ fc1_s, const float* __restrict__ factor,
                             const unsigned* __restrict__ sim,
                             const float* __restrict__ input, const float* __restrict__ degree,
                             const float* __restrict__ adj_row,
                             float* __restrict__ out_h, float* __restrict__ ef_out, int n) {
    const int wid  = (blockIdx.x * blockDim.x + threadIdx.x) >> 6;
    const int lane = threadIdx.x & 63;
    if (wid >= n) return;
    const int end = row_end[wid];
    const int beg = end - cnt[wid];
    const float fnode = factor[wid];
    float acc0 = 0.f, acc1 = 0.f, efsum = 0.f;
    int p = beg;
    for (; p + 4 <= end; p += 4) {
        const int2 de0 = sorted_de[p + 0];
        const int2 de1 = sorted_de[p + 1];
        const int2 de2 = sorted_de[p + 2];
        const int2 de3 = sorted_de[p + 3];
        const float ef0 = fnode * factor[de0.x] * fc1_s[p + 0];
        const float ef1 = fnode * factor[de1.x] * fc1_s[p + 1];
        const float ef2 = fnode * factor[de2.x] * fc1_s[p + 2];
        const float ef3 = fnode * factor[de3.x] * fc1_s[p + 3];
        if (USEBF) {
            const unsigned u0 = sim[(size_t)de0.x * 64 + lane];
            const unsigned u1 = sim[(size_t)de1.x * 64 + lane];
            const unsigned u2 = sim[(size_t)de2.x * 64 + lane];
            const unsigned u3 = sim[(size_t)de3.x * 64 + lane];
            acc0 += ef0 * __uint_as_float(u0 << 16);
            acc1 += ef0 * __uint_as_float(u0 & 0xffff0000u);
            acc0 += ef1 * __uint_as_float(u1 << 16);
            acc1 += ef1 * __uint_as_float(u1 & 0xffff0000u);
            acc0 += ef2 * __uint_as_float(u2 << 16);
            acc1 += ef2 * __uint_as_float(u2 & 0xffff0000u);
            acc0 += ef3 * __uint_as_float(u3 << 16);
            acc1 += ef3 * __uint_as_float(u3 & 0xffff0000u);
        } else {
            const float2 v0 = *(const float2*)(input + (size_t)de0.x * F_IN + 2 * lane);
            const float2 v1 = *(const float2*)(input + (size_t)de1.x * F_IN + 2 * lane);
            const float2 v2 = *(const float2*)(input + (size_t)de2.x * F_IN + 2 * lane);
            const float2 v3 = *(const float2*)(input + (size_t)de3.x * F_IN + 2 * lane);
            const float w0 = ef0 * degree[de0.x];
            const float w1 = ef1 * degree[de1.x];
            const float w2 = ef2 * degree[de2.x];
            const float w3 = ef3 * degree[de3.x];
            acc0 += w0 * v0.x; acc1 += w0 * v0.y;
            acc0 += w1 * v1.x; acc1 += w1 * v1.y;
            acc0 += w2 * v2.x; acc1 += w2 * v2.y;
            acc0 += w3 * v3.x; acc1 += w3 * v3.y;
        }
        efsum += (ef0 + ef1) + (ef2 + ef3);
        if (lane == ((p + 0) & 63)) ef_out[de0.y] = ef0;
        if (lane == ((p + 1) & 63)) ef_out[de1.y] = ef1;
        if (lane == ((p + 2) & 63)) ef_out[de2.y] = ef2;
        if (lane == ((p + 3) & 63)) ef_out[de3.y] = ef3;
    }
    for (; p < end; ++p) {
        const int2 de = sorted_de[p];
        const float ef = fnode * factor[de.x] * fc1_s[p];
        if (lane == (p & 63)) ef_out[de.y] = ef;
        efsum += ef;
        if (USEBF) {
            const unsigned u = sim[(size_t)de.x * 64 + lane];
            acc0 += ef * __uint_as_float(u << 16);
            acc1 += ef * __uint_as_float(u & 0xffff0000u);
        } else {
            const float2 v = *(const float2*)(input + (size_t)de.x * F_IN + 2 * lane);
            const float w = ef * degree[de.x];
            acc0 += w * v.x; acc1 += w * v.y;
        }
    }
    const float aggr = efsum / adj_row[wid];
    const float dg = degree[wid];
    const float2 inn = *(const float2*)(input + (size_t)wid * F_IN + 2 * lane);
    float2 o;
    o.x = acc0 * dg + (1.f - aggr) * inn.x;
    o.y = acc1 * dg + (1.f - aggr) * inn.y;
    *(float2*)(out_h + (size_t)wid * F_IN + 2 * lane) = o;
}

extern "C" void kernel_launch(void* const* d_in, const int* in_sizes, int n_in,
                              void* d_out, int out_size, void* d_ws, size_t ws_size,
                              hipStream_t stream) {
    const float* input   = (const float*)d_in[0];
    const int*   edges   = (const int*)  d_in[1];
    const float* adj_row = (const float*)d_in[3];
    const float* degree  = (const float*)d_in[4];
    const float* w_mini  = (const float*)d_in[5];
    const float* b_mini  = (const float*)d_in[6];
    const float* ab      = (const float*)d_in[7];
    const float* lf1_w   = (const float*)d_in[8];
    const float* lf1_b   = (const float*)d_in[9];
    const float* lf2_w   = (const float*)d_in[10];
    const float* lf2_b   = (const float*)d_in[11];

    const int N = in_sizes[0] / F_IN;
    const int E = in_sizes[1] / 2;
    const int* src = edges;
    const int* dst = edges + E;

    float* final_h = (float*)d_out;
    float* ef_out  = (float*)d_out + (size_t)N * F_IN;

    // workspace layout (4-byte elems)
    float* h_mini     = (float*)d_ws;                 // N*16
    float* fc0_s      = h_mini + (size_t)N * AH;      // E
    float* fc1_s      = fc0_s + E;                    // E
    float* factor     = fc1_s + E;                    // N
    float* Cj         = factor + N;                   // 16
    int*   cnt        = (int*)(Cj + 16);              // N
    int*   row_cur    = cnt + N;                      // N
    int*   bsum       = row_cur + N;                  // 1024
    int*   sorted_src = bsum + 1024;                  // E
    int2*  sorted_de  = (int2*)(sorted_src + E);      // E (dst, eid)
    unsigned* sim     = (unsigned*)(sorted_de + E);   // N*64 (optional, bf16 pairs)
    const size_t need_bf16 = ((char*)(sim + (size_t)N * 64)) - (char*)d_ws;
    const int use_bf16 = (ws_size >= need_bf16);

    hipMemsetAsync(cnt, 0, (size_t)N * sizeof(int), stream);

    k_mini<<<(N + 15) / 16, 256, 0, stream>>>(input, w_mini, b_mini, h_mini, N);
    k_prep<<<1, 64, 0, stream>>>(lf1_w, ab, Cj);
    if (use_bf16)
        k_scale<<<(N * 64 + 255) / 256, 256, 0, stream>>>(input, degree, sim, N);
    k_hist<<<(E + 255) / 256, 256, 0, stream>>>(src, cnt, E);
    {
        const int nb = (N + SCAN_B * SCAN_I - 1) / (SCAN_B * SCAN_I);
        k_scan_part<<<nb, SCAN_B, 0, stream>>>(cnt, row_cur, bsum, N);
        k_scan_tops<<<1, SCAN_B, 0, stream>>>(bsum, nb);
        k_scan_add<<<(N + 255) / 256, 256, 0, stream>>>(row_cur, bsum, N);
    }
    k_scatter<<<(E + 255) / 256, 256, 0, stream>>>(src, dst, row_cur, sorted_src, sorted_de, E);
    k_mlp<<<(E + 255) / 256, 256, 0, stream>>>(sorted_src, sorted_de, h_mini,
                                               lf1_w, lf1_b, lf2_w, lf2_b, Cj,
                                               fc0_s, fc1_s, E);
    k_factor<<<(N + 255) / 256, 256, 0, stream>>>(row_cur, cnt, fc0_s, factor, N);
    if (use_bf16)
        k_spmm_final<1><<<(N * 64 + 255) / 256, 256, 0, stream>>>(row_cur, cnt, sorted_de,
                                                                  fc1_s, factor, sim, input, degree,
                                                                  adj_row, final_h, ef_out, N);
    else
        k_spmm_final<0><<<(N * 64 + 255) / 256, 256, 0, stream>>>(row_cur, cnt, sorted_de,
                                                                  fc1_s, factor, (const unsigned*)0,
                                                                  input, degree,
                                                                  adj_row, final_h, ef_out, N);
}

// Round 5
// 410.067 us; speedup vs baseline: 5.9502x; 1.1445x over previous
//
#include <hip/hip_runtime.h>
#include <math.h>

#define F_IN 128
#define AH 16
#define ALPHA 0.2f

__device__ __forceinline__ unsigned f2bf_rn(float x) {
    unsigned u = __float_as_uint(x);
    return (u + 0x7fffu + ((u >> 16) & 1u)) >> 16;
}

// ============ K1: h_mini = input @ w_mini + b_mini  AND  sim = bf16(input*deg)
__global__ void k_mini(const float* __restrict__ input,
                       const float* __restrict__ w,
                       const float* __restrict__ b,
                       const float* __restrict__ degree,
                       float* __restrict__ out,
                       unsigned* __restrict__ sim, int n) {
    __shared__ float ws[F_IN * AH];
    __shared__ float rows[16][F_IN + 1];
    __shared__ float dgs[16];
    for (int i = threadIdx.x; i < F_IN * AH; i += blockDim.x) ws[i] = w[i];
    const int base = blockIdx.x * 16;
    for (int idx = threadIdx.x; idx < 16 * F_IN; idx += blockDim.x) {
        const int l = idx >> 7, f = idx & 127;
        const int node = base + l;
        rows[l][f] = (node < n) ? input[(size_t)node * F_IN + f] : 0.f;
    }
    if (threadIdx.x < 16) {
        const int node = base + threadIdx.x;
        dgs[threadIdx.x] = (node < n) ? degree[node] : 0.f;
    }
    __syncthreads();
    // phase A: projection (each thread one output element)
    {
        const int l = threadIdx.x >> 4;
        const int j = threadIdx.x & 15;
        const int node = base + l;
        if (node < n) {
            float acc = b[j];
            #pragma unroll 8
            for (int f = 0; f < F_IN; ++f) acc += rows[l][f] * ws[f * AH + j];
            out[(size_t)node * AH + j] = acc;
        }
    }
    // phase B: sim packing (16 nodes x 64 pairs)
    for (int idx = threadIdx.x; idx < 16 * 64; idx += blockDim.x) {
        const int l = idx >> 6, pr = idx & 63;
        const int node = base + l;
        if (node < n) {
            const float dg = dgs[l];
            const float x = rows[l][2 * pr]     * dg;
            const float y = rows[l][2 * pr + 1] * dg;
            sim[(size_t)node * 64 + pr] = (f2bf_rn(y) << 16) | f2bf_rn(x);
        }
    }
}

// ============ K-prep: Cj[j] = sum_k ab[k]*(W1[k][j] + W1[16+k][j]) ========
__global__ void k_prep(const float* __restrict__ lf1_w, const float* __restrict__ ab,
                       float* __restrict__ Cj) {
    const int j = threadIdx.x;
    if (j < AH) {
        float c = 0.f;
        for (int k = 0; k < AH; ++k)
            c += ab[k] * (lf1_w[k * AH + j] + lf1_w[(AH + k) * AH + j]);
        Cj[j] = c;
    }
}

// ============ K2: histogram of src ========================================
__global__ void k_hist(const int* __restrict__ src, int* __restrict__ cnt, int e) {
    const int i = blockIdx.x * blockDim.x + threadIdx.x;
    if (i < e) atomicAdd(&cnt[src[i]], 1);
}

// ============ K3: exclusive scan ==========================================
#define SCAN_B 256
#define SCAN_I 4
__global__ void k_scan_part(const int* __restrict__ cnt, int* __restrict__ excl,
                            int* __restrict__ bsum, int n) {
    __shared__ int sh[SCAN_B];
    const int t = threadIdx.x;
    const int base = blockIdx.x * (SCAN_B * SCAN_I) + t * SCAN_I;
    int v[SCAN_I];
    int s = 0;
    #pragma unroll
    for (int k = 0; k < SCAN_I; ++k) { const int i = base + k; v[k] = (i < n) ? cnt[i] : 0; s += v[k]; }
    sh[t] = s; __syncthreads();
    for (int off = 1; off < SCAN_B; off <<= 1) {
        const int x = (t >= off) ? sh[t - off] : 0;
        __syncthreads();
        sh[t] += x;
        __syncthreads();
    }
    int r = sh[t] - s;
    if (t == SCAN_B - 1) bsum[blockIdx.x] = sh[t];
    #pragma unroll
    for (int k = 0; k < SCAN_I; ++k) { const int i = base + k; if (i < n) excl[i] = r; r += v[k]; }
}
__global__ void k_scan_tops(int* __restrict__ bsum, int nb) {
    __shared__ int sh[SCAN_B];
    const int t = threadIdx.x;
    const int v = (t < nb) ? bsum[t] : 0;
    sh[t] = v; __syncthreads();
    for (int off = 1; off < SCAN_B; off <<= 1) {
        const int x = (t >= off) ? sh[t - off] : 0;
        __syncthreads();
        sh[t] += x;
        __syncthreads();
    }
    if (t < nb) bsum[t] = sh[t] - v;
}
__global__ void k_scan_add(int* __restrict__ excl, const int* __restrict__ bsum, int n) {
    const int i = blockIdx.x * blockDim.x + threadIdx.x;
    if (i < n) excl[i] += bsum[i >> 10];
}

// ============ K5: fused edge MLP + CSR scatter (original edge order) ======
#define ROW4(base, val) \
    w = Wv[(base) * 4 + 0]; f0  += (val) * w.x; f1  += (val) * w.y; f2  += (val) * w.z; f3  += (val) * w.w; \
    w = Wv[(base) * 4 + 1]; f4  += (val) * w.x; f5  += (val) * w.y; f6  += (val) * w.z; f7  += (val) * w.w; \
    w = Wv[(base) * 4 + 2]; f8  += (val) * w.x; f9  += (val) * w.y; f10 += (val) * w.z; f11 += (val) * w.w; \
    w = Wv[(base) * 4 + 3]; f12 += (val) * w.x; f13 += (val) * w.y; f14 += (val) * w.z; f15 += (val) * w.w;

#define KSTEP(k, hs, hd) { \
    const float df_ = fabsf((hd) - (hs)); float4 w; \
    ROW4((k), (hs)) ROW4((16 + (k)), (hd)) ROW4((32 + (k)), df_) }

#define TAIL(j, fj) { \
    const float w2_ = lf2_w[j]; const float c_ = Cj[j]; \
    acc0 += w2_ * ((fj) > 0.f ? (fj) : ALPHA * (fj)); \
    const float v1_ = (fj) + c_; \
    acc1 += w2_ * (v1_ > 0.f ? v1_ : ALPHA * v1_); }

__global__ __launch_bounds__(256, 4)
void k_mlp(const int* __restrict__ src, const int* __restrict__ dst,
           const float* __restrict__ h,
           const float* __restrict__ lf1_w, const float* __restrict__ lf1_b,
           const float* __restrict__ lf2_w, const float* __restrict__ lf2_b,
           const float* __restrict__ Cj,
           int* __restrict__ row_cur,
           int2* __restrict__ sorted_de, float2* __restrict__ fcp, int e) {
    const int i = blockIdx.x * blockDim.x + threadIdx.x;
    if (i >= e) return;
    const int s = src[i];
    const int d = dst[i];
    const float4* __restrict__ ps = (const float4*)(h + (size_t)s * AH);
    const float4* __restrict__ pd = (const float4*)(h + (size_t)d * AH);
    const float4* __restrict__ Wv = (const float4*)lf1_w;

    float f0  = lf1_b[0],  f1  = lf1_b[1],  f2  = lf1_b[2],  f3  = lf1_b[3];
    float f4  = lf1_b[4],  f5  = lf1_b[5],  f6  = lf1_b[6],  f7  = lf1_b[7];
    float f8  = lf1_b[8],  f9  = lf1_b[9],  f10 = lf1_b[10], f11 = lf1_b[11];
    float f12 = lf1_b[12], f13 = lf1_b[13], f14 = lf1_b[14], f15 = lf1_b[15];

    float4 a, b4;
    a = ps[0]; b4 = pd[0];
    KSTEP(0,  a.x, b4.x) KSTEP(1,  a.y, b4.y) KSTEP(2,  a.z, b4.z) KSTEP(3,  a.w, b4.w)
    a = ps[1]; b4 = pd[1];
    KSTEP(4,  a.x, b4.x) KSTEP(5,  a.y, b4.y) KSTEP(6,  a.z, b4.z) KSTEP(7,  a.w, b4.w)
    a = ps[2]; b4 = pd[2];
    KSTEP(8,  a.x, b4.x) KSTEP(9,  a.y, b4.y) KSTEP(10, a.z, b4.z) KSTEP(11, a.w, b4.w)
    a = ps[3]; b4 = pd[3];
    KSTEP(12, a.x, b4.x) KSTEP(13, a.y, b4.y) KSTEP(14, a.z, b4.z) KSTEP(15, a.w, b4.w)

    float acc0 = lf2_b[0], acc1 = lf2_b[0];
    TAIL(0, f0)  TAIL(1, f1)  TAIL(2, f2)   TAIL(3, f3)
    TAIL(4, f4)  TAIL(5, f5)  TAIL(6, f6)   TAIL(7, f7)
    TAIL(8, f8)  TAIL(9, f9)  TAIL(10, f10) TAIL(11, f11)
    TAIL(12, f12) TAIL(13, f13) TAIL(14, f14) TAIL(15, f15)

    const float fc0 = 1.f / (1.f + expf(-acc0));
    const float fc1 = 1.f / (1.f + expf(-acc1));
    const int p = atomicAdd(&row_cur[s], 1);
    sorted_de[p] = make_int2(d, i);
    fcp[p] = make_float2(fc0, fc1);
}

// ============ K6: per-node factor =========================================
__global__ void k_factor(const int* __restrict__ row_end, const int* __restrict__ cnt,
                         const float2* __restrict__ fcp, float* __restrict__ factor, int n) {
    const int i = blockIdx.x * blockDim.x + threadIdx.x;
    if (i >= n) return;
    const int end = row_end[i];
    const int c = cnt[i];
    float s = 0.f;
    for (int p = end - c; p < end; ++p) s += fcp[p].x;
    factor[i] = s / fmaxf((float)c, 1.f);
}

// ============ K7: fused ef + row-sum + SpMM + final combine ===============
// One wave per node. Phase 1: lanes compute ef for up to 64 edges in
// parallel (coalesced loads, direct ef_out store), stash (ef,dst) in LDS.
// Phase 2: uniform ds_read broadcast, 8 sim-gathers in flight, pure fma.
__global__ void k_spmm_final(const int* __restrict__ row_end, const int* __restrict__ cnt,
                             const int2* __restrict__ sorted_de,
                             const float2* __restrict__ fcp,
                             const float* __restrict__ factor,
                             const unsigned* __restrict__ sim,
                             const float* __restrict__ input,
                             const float* __restrict__ degree,
                             const float* __restrict__ adj_row,
                             float* __restrict__ out_h, float* __restrict__ ef_out, int n) {
    __shared__ float2 sh[256];            // per-wave 64-entry slot: (ef, bits(dst))
    const int wid  = (blockIdx.x * blockDim.x + threadIdx.x) >> 6;
    const int lane = threadIdx.x & 63;
    const int sbase = threadIdx.x & ~63;
    if (wid >= n) return;
    const int end = row_end[wid];
    const int beg = end - cnt[wid];
    const float fnode = factor[wid];
    float acc0 = 0.f, acc1 = 0.f, efl = 0.f;
    for (int base = beg; base < end; base += 64) {
        const int rem = end - base;
        const int mm = rem < 64 ? rem : 64;
        float ef = 0.f; int dl = 0;
        if (lane < mm) {
            const int2 de = sorted_de[base + lane];
            const float2 fc = fcp[base + lane];
            ef = fnode * factor[de.x] * fc.y;
            dl = de.x;
            ef_out[de.y] = ef;
        }
        efl += ef;
        sh[sbase + lane] = make_float2(ef, __int_as_float(dl));
        for (int j = 0; j < mm; j += 8) {
            float2 t0 = sh[sbase + j + 0];
            float2 t1 = sh[sbase + j + 1];
            float2 t2 = sh[sbase + j + 2];
            float2 t3 = sh[sbase + j + 3];
            float2 t4 = sh[sbase + j + 4];
            float2 t5 = sh[sbase + j + 5];
            float2 t6 = sh[sbase + j + 6];
            float2 t7 = sh[sbase + j + 7];
            const unsigned u0 = sim[(size_t)__float_as_int(t0.y) * 64 + lane];
            const unsigned u1 = sim[(size_t)__float_as_int(t1.y) * 64 + lane];
            const unsigned u2 = sim[(size_t)__float_as_int(t2.y) * 64 + lane];
            const unsigned u3 = sim[(size_t)__float_as_int(t3.y) * 64 + lane];
            const unsigned u4 = sim[(size_t)__float_as_int(t4.y) * 64 + lane];
            const unsigned u5 = sim[(size_t)__float_as_int(t5.y) * 64 + lane];
            const unsigned u6 = sim[(size_t)__float_as_int(t6.y) * 64 + lane];
            const unsigned u7 = sim[(size_t)__float_as_int(t7.y) * 64 + lane];
            acc0 += t0.x * __uint_as_float(u0 << 16);
            acc1 += t0.x * __uint_as_float(u0 & 0xffff0000u);
            acc0 += t1.x * __uint_as_float(u1 << 16);
            acc1 += t1.x * __uint_as_float(u1 & 0xffff0000u);
            acc0 += t2.x * __uint_as_float(u2 << 16);
            acc1 += t2.x * __uint_as_float(u2 & 0xffff0000u);
            acc0 += t3.x * __uint_as_float(u3 << 16);
            acc1 += t3.x * __uint_as_float(u3 & 0xffff0000u);
            acc0 += t4.x * __uint_as_float(u4 << 16);
            acc1 += t4.x * __uint_as_float(u4 & 0xffff0000u);
            acc0 += t5.x * __uint_as_float(u5 << 16);
            acc1 += t5.x * __uint_as_float(u5 & 0xffff0000u);
            acc0 += t6.x * __uint_as_float(u6 << 16);
            acc1 += t6.x * __uint_as_float(u6 & 0xffff0000u);
            acc0 += t7.x * __uint_as_float(u7 << 16);
            acc1 += t7.x * __uint_as_float(u7 & 0xffff0000u);
        }
    }
    // wave-reduce efl (lanes past row end contributed 0)
    for (int off = 32; off > 0; off >>= 1) efl += __shfl_xor(efl, off);
    const float aggr = efl / adj_row[wid];
    const float dg = degree[wid];
    const float2 inn = *(const float2*)(input + (size_t)wid * F_IN + 2 * lane);
    float2 o;
    o.x = acc0 * dg + (1.f - aggr) * inn.x;
    o.y = acc1 * dg + (1.f - aggr) * inn.y;
    *(float2*)(out_h + (size_t)wid * F_IN + 2 * lane) = o;
}

extern "C" void kernel_launch(void* const* d_in, const int* in_sizes, int n_in,
                              void* d_out, int out_size, void* d_ws, size_t ws_size,
                              hipStream_t stream) {
    const float* input   = (const float*)d_in[0];
    const int*   edges   = (const int*)  d_in[1];
    const float* adj_row = (const float*)d_in[3];
    const float* degree  = (const float*)d_in[4];
    const float* w_mini  = (const float*)d_in[5];
    const float* b_mini  = (const float*)d_in[6];
    const float* ab      = (const float*)d_in[7];
    const float* lf1_w   = (const float*)d_in[8];
    const float* lf1_b   = (const float*)d_in[9];
    const float* lf2_w   = (const float*)d_in[10];
    const float* lf2_b   = (const float*)d_in[11];

    const int N = in_sizes[0] / F_IN;
    const int E = in_sizes[1] / 2;
    const int* src = edges;
    const int* dst = edges + E;

    float* final_h = (float*)d_out;
    float* ef_out  = (float*)d_out + (size_t)N * F_IN;

    // workspace layout (4-byte elems; N,E even -> 8B alignment holds)
    float*  h_mini    = (float*)d_ws;                 // N*16
    float2* fcp       = (float2*)(h_mini + (size_t)N * AH); // E pairs (fc0,fc1)
    float*  factor    = (float*)(fcp + E);            // N
    float*  Cj        = factor + N;                   // 16
    int*    cnt       = (int*)(Cj + 16);              // N
    int*    row_cur   = cnt + N;                      // N
    int*    bsum      = row_cur + N;                  // 1024
    int2*   sorted_de = (int2*)(bsum + 1024);         // E (dst, eid)
    unsigned* sim     = (unsigned*)(sorted_de + E);   // N*64 bf16 pairs

    hipMemsetAsync(cnt, 0, (size_t)N * sizeof(int), stream);

    k_mini<<<(N + 15) / 16, 256, 0, stream>>>(input, w_mini, b_mini, degree, h_mini, sim, N);
    k_prep<<<1, 64, 0, stream>>>(lf1_w, ab, Cj);
    k_hist<<<(E + 255) / 256, 256, 0, stream>>>(src, cnt, E);
    {
        const int nb = (N + SCAN_B * SCAN_I - 1) / (SCAN_B * SCAN_I);
        k_scan_part<<<nb, SCAN_B, 0, stream>>>(cnt, row_cur, bsum, N);
        k_scan_tops<<<1, SCAN_B, 0, stream>>>(bsum, nb);
        k_scan_add<<<(N + 255) / 256, 256, 0, stream>>>(row_cur, bsum, N);
    }
    k_mlp<<<(E + 255) / 256, 256, 0, stream>>>(src, dst, h_mini,
                                               lf1_w, lf1_b, lf2_w, lf2_b, Cj,
                                               row_cur, sorted_de, fcp, E);
    k_factor<<<(N + 255) / 256, 256, 0, stream>>>(row_cur, cnt, fcp, factor, N);
    k_spmm_final<<<(N * 64 + 255) / 256, 256, 0, stream>>>(row_cur, cnt, sorted_de, fcp,
                                                           factor, sim, input, degree, adj_row,
                                                           final_h, ef_out, N);
}